// Round 15
// baseline (441.093 us; speedup 1.0000x reference)
//
#include <hip/hip_runtime.h>
#include <hip/hip_bf16.h>

typedef unsigned int u32;
typedef unsigned short u16;
typedef _Float16 f16x2 __attribute__((ext_vector_type(2)));
typedef _Float16 f16x8 __attribute__((ext_vector_type(8)));
typedef float f32x4 __attribute__((ext_vector_type(4)));

#define NN 50000
#define EE 800000
#define A1_BLOCKS 4096
#define SCAN_B ((NN + 255) / 256)   // 196

__device__ __forceinline__ f16x2 ash(u32 u) { union { u32 u; f16x2 h; } c; c.u = u; return c.h; }
__device__ __forceinline__ u32 h2u(f16x2 h) { union { u32 u; f16x2 h; } c; c.h = h; return c.u; }
__device__ __forceinline__ u16 f2h(float v) { _Float16 h = (_Float16)v; return *(u16*)&h; }
__device__ __forceinline__ u32 pack2h(float a, float b) {
    return (u32)f2h(a) | ((u32)f2h(b) << 16);
}
__device__ __forceinline__ float elu(float v) { return v > 0.f ? v : __expf(v) - 1.f; }

// ---------------- prep: weight transpose->f16 (blocks 0-575) + deg zero (blocks 576+) ----------------

__global__ __launch_bounds__(256) void gat_prep_r15(const float* __restrict__ W1,
                                                    const float* __restrict__ W2,
                                                    const float* __restrict__ W3,
                                                    u16* __restrict__ W1t,
                                                    u16* __restrict__ W2t,
                                                    u16* __restrict__ W3t,
                                                    int* __restrict__ deg) {
    int b = blockIdx.x, t = threadIdx.x;
    if (b < 256) {
        if (t < 128) W1t[(long)b * 128 + t] = f2h(W1[(long)t * 256 + b]);
    } else if (b < 512) {
        int n = b - 256;
        W2t[(long)n * 256 + t] = f2h(W2[(long)t * 256 + n]);
    } else if (b < 576) {
        int n = b - 512;
        W3t[(long)n * 256 + t] = f2h(W3[(long)t * 64 + n]);
    } else {
        int i = (b - 576) * 256 + t;
        if (i < NN) deg[i] = 0;
    }
}

// ---------------- CSR build (group edges by dst) ----------------

__global__ void gat_count_r15(const int* __restrict__ dst, int* __restrict__ deg) {
    int e = blockIdx.x * 256 + threadIdx.x;
    if (e < EE) atomicAdd(&deg[dst[e]], 1);
}

__global__ __launch_bounds__(256) void gat_scana_r15(const int* __restrict__ deg,
                                                     int* __restrict__ bsum) {
    __shared__ int s[256];
    int t = threadIdx.x;
    int i = blockIdx.x * 256 + t;
    s[t] = (i < NN) ? deg[i] : 0;
    __syncthreads();
    for (int o = 128; o > 0; o >>= 1) {
        if (t < o) s[t] += s[t + o];
        __syncthreads();
    }
    if (t == 0) bsum[blockIdx.x] = s[0];
}

__global__ __launch_bounds__(256) void gat_scanc_r15(const int* __restrict__ deg,
                                                     const int* __restrict__ bsum,
                                                     int* __restrict__ row_ptr,
                                                     int* __restrict__ cursor) {
    __shared__ int sb[256];
    __shared__ int s[256];
    int t = threadIdx.x;
    sb[t] = (t < SCAN_B) ? bsum[t] : 0;
    __syncthreads();
    for (int o = 1; o < 256; o <<= 1) {
        int u = (t >= o) ? sb[t - o] : 0;
        __syncthreads();
        sb[t] += u;
        __syncthreads();
    }
    int boff = (blockIdx.x == 0) ? 0 : sb[blockIdx.x - 1];
    if (blockIdx.x == 0 && t == 0) row_ptr[NN] = sb[SCAN_B - 1];
    int i = blockIdx.x * 256 + t;
    int v = (i < NN) ? deg[i] : 0;
    s[t] = v;
    __syncthreads();
    for (int o = 1; o < 256; o <<= 1) {
        int u = (t >= o) ? s[t - o] : 0;
        __syncthreads();
        s[t] += u;
        __syncthreads();
    }
    if (i < NN) {
        int excl = s[t] - v + boff;
        row_ptr[i] = excl;
        cursor[i]  = excl;
    }
}

__global__ void gat_scatter_r15(const int* __restrict__ src, const int* __restrict__ dst,
                                int* __restrict__ cursor, int* __restrict__ esrc) {
    int e = blockIdx.x * 256 + threadIdx.x;
    if (e < EE) {
        int pos = atomicAdd(&cursor[dst[e]], 1);
        esrc[pos] = src[e];
    }
}

// ---------------- MFMA GEMM, BN=128: C[M,Nc](f16) = A[M,K] @ Wt^T + bias ----------------
// BM=64, BN=128, BK=32, 4 waves; wave w covers cols [32w,32w+32) x all 64 rows
// (4 m-tiles x 2 n-tiles = 8 mfma_f32_16x16x32_f16 per k-iter). Halves A re-reads vs BN=64.

template <int AHF>
__global__ __launch_bounds__(256) void gat_gemm128_r15(const void* __restrict__ Ain,
                                                       const u16* __restrict__ Wt,
                                                       const float* __restrict__ bias,
                                                       u16* __restrict__ C,
                                                       int M, int K, int Nc) {
    __shared__ __align__(16) u16 As[64 * 40];
    __shared__ __align__(16) u16 Bs[128 * 40];
    const int t    = threadIdx.x;
    const int bm   = blockIdx.x * 64;
    const int bn   = blockIdx.y * 128;
    const int w    = t >> 6;
    const int lane = t & 63;
    const int sm   = t >> 2;        // A staging row 0..63
    const int sk   = (t & 3) * 8;   // A staging k offset
    const int fq   = (lane >> 4) * 8;
    const int fr   = lane & 15;
    const int nbase = w * 32;

    f32x4 acc[4][2] = {};

    for (int k0 = 0; k0 < K; k0 += 32) {
        // stage A tile (64 x 32)
        {
            int gr = bm + sm;
            f16x8 av = {};
            if (gr < M) {
                if (AHF) {
                    av = *(const f16x8*)((const u16*)Ain + (long)gr * K + k0 + sk);
                } else {
                    const float* p = (const float*)Ain + (long)gr * K + k0 + sk;
                    #pragma unroll
                    for (int i = 0; i < 8; ++i) av[i] = (_Float16)p[i];
                }
            }
            *(f16x8*)&As[sm * 40 + sk] = av;
        }
        // stage B tile (128 x 32): 512 8-elem chunks, 2 per thread
        #pragma unroll
        for (int i = 0; i < 2; ++i) {
            int tau = t + i * 256;
            int row = tau >> 2, ck = (tau & 3) * 8;
            f16x8 bv = *(const f16x8*)(Wt + (long)(bn + row) * K + k0 + ck);
            *(f16x8*)&Bs[row * 40 + ck] = bv;
        }
        __syncthreads();
        f16x8 afr[4], bfr[2];
        #pragma unroll
        for (int mt = 0; mt < 4; ++mt)
            afr[mt] = *(const f16x8*)&As[(mt * 16 + fr) * 40 + fq];
        #pragma unroll
        for (int nt = 0; nt < 2; ++nt)
            bfr[nt] = *(const f16x8*)&Bs[(nbase + nt * 16 + fr) * 40 + fq];
        #pragma unroll
        for (int mt = 0; mt < 4; ++mt)
            #pragma unroll
            for (int nt = 0; nt < 2; ++nt)
                acc[mt][nt] = __builtin_amdgcn_mfma_f32_16x16x32_f16(
                    afr[mt], bfr[nt], acc[mt][nt], 0, 0, 0);
        __syncthreads();
    }
    #pragma unroll
    for (int mt = 0; mt < 4; ++mt) {
        #pragma unroll
        for (int r = 0; r < 4; ++r) {
            int row = bm + mt * 16 + (lane >> 4) * 4 + r;
            if (row >= M) continue;
            #pragma unroll
            for (int nt = 0; nt < 2; ++nt) {
                int col = bn + nbase + nt * 16 + fr;
                C[(long)row * Nc + col] = f2h(acc[mt][nt][r] + bias[col]);
            }
        }
    }
}

// ---------------- MFMA GEMM, BN=64 (verified R7 structure) — used for layer 3 (Nc=64) ----------------

__global__ __launch_bounds__(256) void gat_gemm64_r15(const u16* __restrict__ Ain,
                                                      const u16* __restrict__ Wt,
                                                      const float* __restrict__ bias,
                                                      u16* __restrict__ C,
                                                      int M, int K, int Nc) {
    __shared__ __align__(16) u16 As[64 * 40];
    __shared__ __align__(16) u16 Bs[64 * 40];
    const int t    = threadIdx.x;
    const int bm   = blockIdx.x * 64;
    const int bn   = blockIdx.y * 64;
    const int w    = t >> 6;
    const int lane = t & 63;
    const int sm   = t >> 2;
    const int sk   = (t & 3) * 8;
    const int mbase = (w & 1) * 32;
    const int nbase = (w >> 1) * 32;
    const int fq    = (lane >> 4) * 8;
    const int fr    = lane & 15;

    f32x4 acc[2][2] = {};

    for (int k0 = 0; k0 < K; k0 += 32) {
        {
            int gr = bm + sm;
            f16x8 av = {};
            if (gr < M) av = *(const f16x8*)(Ain + (long)gr * K + k0 + sk);
            *(f16x8*)&As[sm * 40 + sk] = av;
        }
        {
            f16x8 bv = *(const f16x8*)(Wt + (long)(bn + sm) * K + k0 + sk);
            *(f16x8*)&Bs[sm * 40 + sk] = bv;
        }
        __syncthreads();
        f16x8 afr[2], bfr[2];
        #pragma unroll
        for (int mt = 0; mt < 2; ++mt)
            afr[mt] = *(const f16x8*)&As[(mbase + mt * 16 + fr) * 40 + fq];
        #pragma unroll
        for (int nt = 0; nt < 2; ++nt)
            bfr[nt] = *(const f16x8*)&Bs[(nbase + nt * 16 + fr) * 40 + fq];
        #pragma unroll
        for (int mt = 0; mt < 2; ++mt)
            #pragma unroll
            for (int nt = 0; nt < 2; ++nt)
                acc[mt][nt] = __builtin_amdgcn_mfma_f32_16x16x32_f16(
                    afr[mt], bfr[nt], acc[mt][nt], 0, 0, 0);
        __syncthreads();
    }
    #pragma unroll
    for (int mt = 0; mt < 2; ++mt) {
        #pragma unroll
        for (int r = 0; r < 4; ++r) {
            int row = bm + mbase + mt * 16 + (lane >> 4) * 4 + r;
            if (row >= M) continue;
            #pragma unroll
            for (int nt = 0; nt < 2; ++nt) {
                int col = bn + nbase + nt * 16 + fr;
                C[(long)row * Nc + col] = f2h(acc[mt][nt][r] + bias[col]);
            }
        }
    }
}

// ---------------- Attention layers 1&2: H=8, D=32, half-wave pairing, packed f16, pipelined gather ----

__global__ __launch_bounds__(256) void gat_attn8_r15(const uint4* __restrict__ h4,
                                                     const int* __restrict__ row_ptr,
                                                     const int* __restrict__ esrc,
                                                     const float* __restrict__ attn,
                                                     uint4* __restrict__ act4) {
    int t = threadIdx.x;
    int lane = t & 63, wv = t >> 6;
    int hf = lane >> 5, sub = lane & 31;
    int n = blockIdx.x * 4 + wv;          // grid = NN/4 exactly
    float4 av0 = ((const float4*)attn)[sub * 2];
    float4 av1 = ((const float4*)attn)[sub * 2 + 1];
    f16x2 aw0 = {(_Float16)av0.x, (_Float16)av0.y};
    f16x2 aw1 = {(_Float16)av0.z, (_Float16)av0.w};
    f16x2 aw2 = {(_Float16)av1.x, (_Float16)av1.y};
    f16x2 aw3 = {(_Float16)av1.z, (_Float16)av1.w};
    const f16x2 c02 = {(_Float16)0.2f, (_Float16)0.2f};
    uint4 ud = h4[(long)n * 32 + sub];
    f16x2 hd0 = ash(ud.x), hd1 = ash(ud.y), hd2 = ash(ud.z), hd3 = ash(ud.w);
    int lo = row_ptr[n], hi = row_ptr[n + 1];

    auto fetchpair = [&](int e) -> uint4 {
        int s0 = __builtin_amdgcn_readfirstlane(esrc[e]);
        int e1 = (e + 1 < hi) ? e + 1 : e;
        int s1 = __builtin_amdgcn_readfirstlane(esrc[e1]);
        int srow = hf ? s1 : s0;
        return h4[(long)srow * 32 + sub];
    };

    float l = 0.f;
    f16x2 O0 = {}, O1 = {}, O2 = {}, O3 = {};
    uint4 u = fetchpair(lo);                 // deg >= 1 always
    for (int e = lo; e < hi; e += 2) {
        uint4 un = {};
        if (e + 2 < hi) un = fetchpair(e + 2);   // overlaps with math below
        f16x2 x0 = ash(u.x), x1 = ash(u.y), x2 = ash(u.z), x3 = ash(u.w);
        f16x2 v0 = x0 + hd0, v1 = x1 + hd1, v2 = x2 + hd2, v3 = x3 + hd3;
        f16x2 r0 = __builtin_elementwise_max(v0, v0 * c02);
        f16x2 r1 = __builtin_elementwise_max(v1, v1 * c02);
        f16x2 r2 = __builtin_elementwise_max(v2, v2 * c02);
        f16x2 r3 = __builtin_elementwise_max(v3, v3 * c02);
        f16x2 acc = r0 * aw0;
        acc += r1 * aw1;
        acc += r2 * aw2;
        acc += r3 * aw3;
        float p = (float)acc.x + (float)acc.y;
        p += __shfl_xor(p, 1);
        p += __shfl_xor(p, 2);
        float w = __expf(p);
        if (hf && e + 1 >= hi) w = 0.f;      // odd tail: upper half contributes 0
        l += w;
        _Float16 wh = (_Float16)w;
        f16x2 w2 = {wh, wh};
        O0 += x0 * w2; O1 += x1 * w2; O2 += x2 * w2; O3 += x3 * w2;
        u = un;
    }
    // merge halves (even-edge + odd-edge partial sums)
    l += __shfl_xor(l, 32);
    O0 += ash(__shfl_xor((int)h2u(O0), 32));
    O1 += ash(__shfl_xor((int)h2u(O1), 32));
    O2 += ash(__shfl_xor((int)h2u(O2), 32));
    O3 += ash(__shfl_xor((int)h2u(O3), 32));
    float rinv = 1.f / l;
    if (hf == 0) {
        uint4 outv;
        outv.x = pack2h(elu((float)O0.x * rinv), elu((float)O0.y * rinv));
        outv.y = pack2h(elu((float)O1.x * rinv), elu((float)O1.y * rinv));
        outv.z = pack2h(elu((float)O2.x * rinv), elu((float)O2.y * rinv));
        outv.w = pack2h(elu((float)O3.x * rinv), elu((float)O3.y * rinv));
        act4[(long)n * 32 + sub] = outv;
    }
}

// ---------------- Attention layer 3: H=1, D=64, quarter-wave, packed f16, pipelined + max-pool ------

__global__ __launch_bounds__(256) void gat_attn1_r15(const uint2* __restrict__ h2,
                                                     const int* __restrict__ row_ptr,
                                                     const int* __restrict__ esrc,
                                                     const float* __restrict__ attn,
                                                     float* __restrict__ blockmax) {
    int t = threadIdx.x;
    int lane = t & 63, wv = t >> 6;
    int g = lane >> 4, sub = lane & 15;
    float4 aq = ((const float4*)attn)[sub];
    f16x2 aw0 = {(_Float16)aq.x, (_Float16)aq.y};
    f16x2 aw1 = {(_Float16)aq.z, (_Float16)aq.w};
    const f16x2 c02 = {(_Float16)0.2f, (_Float16)0.2f};
    float b0 = -1e30f, b1 = -1e30f, b2 = -1e30f, b3 = -1e30f;
    for (int n = blockIdx.x * 4 + wv; n < NN; n += gridDim.x * 4) {
        uint2 ud = h2[(long)n * 16 + sub];
        f16x2 hd0 = ash(ud.x), hd1 = ash(ud.y);
        int lo = row_ptr[n], hi = row_ptr[n + 1];

        auto fetch = [&](int e) -> uint2 {
            int eg = e + g;
            int s = esrc[(eg < hi) ? eg : hi - 1];
            return h2[(long)s * 16 + sub];
        };

        float l = 0.f;
        f16x2 O0 = {}, O1 = {};
        uint2 u = fetch(lo);
        for (int e = lo; e < hi; e += 4) {
            uint2 un = {};
            if (e + 4 < hi) un = fetch(e + 4);
            f16x2 x0 = ash(u.x), x1 = ash(u.y);
            f16x2 v0 = x0 + hd0, v1 = x1 + hd1;
            f16x2 r0 = __builtin_elementwise_max(v0, v0 * c02);
            f16x2 r1 = __builtin_elementwise_max(v1, v1 * c02);
            f16x2 acc = r0 * aw0;
            acc += r1 * aw1;
            float p = (float)acc.x + (float)acc.y;
            p += __shfl_xor(p, 1);
            p += __shfl_xor(p, 2);
            p += __shfl_xor(p, 4);
            p += __shfl_xor(p, 8);
            float w = (e + g < hi) ? __expf(p) : 0.f;
            l += w;
            _Float16 wh = (_Float16)w;
            f16x2 w2 = {wh, wh};
            O0 += x0 * w2;
            O1 += x1 * w2;
            u = un;
        }
        // merge the 4 edge-groups
        l += __shfl_xor(l, 16); l += __shfl_xor(l, 32);
        O0 += ash(__shfl_xor((int)h2u(O0), 16));
        O0 += ash(__shfl_xor((int)h2u(O0), 32));
        O1 += ash(__shfl_xor((int)h2u(O1), 16));
        O1 += ash(__shfl_xor((int)h2u(O1), 32));
        float rinv = 1.f / l;
        b0 = fmaxf(b0, (float)O0.x * rinv); b1 = fmaxf(b1, (float)O0.y * rinv);
        b2 = fmaxf(b2, (float)O1.x * rinv); b3 = fmaxf(b3, (float)O1.y * rinv);
    }
    __shared__ float4 sm4[4][16];
    if (lane < 16) { float4 v; v.x = b0; v.y = b1; v.z = b2; v.w = b3; sm4[wv][sub] = v; }
    __syncthreads();
    if (wv == 0 && lane < 16) {
        float4 r = sm4[0][sub];
        #pragma unroll
        for (int i = 1; i < 4; ++i) {
            float4 q = sm4[i][sub];
            r.x = fmaxf(r.x, q.x); r.y = fmaxf(r.y, q.y);
            r.z = fmaxf(r.z, q.z); r.w = fmaxf(r.w, q.w);
        }
        ((float4*)(blockmax + (long)blockIdx.x * 64))[sub] = r;
    }
}

__global__ __launch_bounds__(1024) void gat_final_r15(const float* __restrict__ blockmax,
                                                      float* __restrict__ out) {
    __shared__ float sm[16][64];
    int t = threadIdx.x;
    int lane = t & 63, wv = t >> 6;
    float v = -1e30f;
    for (int b = wv; b < A1_BLOCKS; b += 16)
        v = fmaxf(v, blockmax[(long)b * 64 + lane]);
    sm[wv][lane] = v;
    __syncthreads();
    if (wv == 0) {
        float r = sm[0][lane];
        #pragma unroll
        for (int i = 1; i < 16; ++i) r = fmaxf(r, sm[i][lane]);
        out[lane] = r;
    }
}

// ---------------- launch ----------------

extern "C" void kernel_launch(void* const* d_in, const int* in_sizes, int n_in,
                              void* d_out, int out_size, void* d_ws, size_t ws_size,
                              hipStream_t stream) {
    const float* x     = (const float*)d_in[0];
    const int*   src   = (const int*)  d_in[1];
    const int*   dst   = (const int*)  d_in[2];
    const float* W1    = (const float*)d_in[3];
    const float* b1    = (const float*)d_in[4];
    const float* attn1 = (const float*)d_in[5];
    const float* W2    = (const float*)d_in[6];
    const float* b2    = (const float*)d_in[7];
    const float* attn2 = (const float*)d_in[8];
    const float* W3    = (const float*)d_in[9];
    const float* b3    = (const float*)d_in[10];
    const float* attn3 = (const float*)d_in[11];
    float* out = (float*)d_out;

    char* ws = (char*)d_ws;
    size_t off = 0;
    auto carve = [&](size_t bytes) { void* p = ws + off; off += (bytes + 255) & ~size_t(255); return p; };
    u16*   P        = (u16*)  carve((size_t)NN * 256 * 2);
    u16*   Q        = (u16*)  carve((size_t)NN * 256 * 2);
    u16*   h3       = (u16*)  carve((size_t)NN * 64 * 2);
    int*   row_ptr  = (int*)  carve((size_t)(NN + 1) * 4);
    int*   deg      = (int*)  carve((size_t)NN * 4);
    int*   cursor   = (int*)  carve((size_t)NN * 4);
    int*   esrc     = (int*)  carve((size_t)EE * 4);
    float* blockmax = (float*)carve((size_t)A1_BLOCKS * 64 * 4);
    int*   bsum     = (int*)  carve((size_t)SCAN_B * 4);
    u16*   W1t      = (u16*)  carve((size_t)256 * 128 * 2);
    u16*   W2t      = (u16*)  carve((size_t)256 * 256 * 2);
    u16*   W3t      = (u16*)  carve((size_t)64 * 256 * 2);

    // prep (weights + deg zero) + CSR by dst
    gat_prep_r15<<<576 + SCAN_B, 256, 0, stream>>>(W1, W2, W3, W1t, W2t, W3t, deg);
    gat_count_r15<<<(EE + 255) / 256, 256, 0, stream>>>(dst, deg);
    gat_scana_r15<<<SCAN_B, 256, 0, stream>>>(deg, bsum);
    gat_scanc_r15<<<SCAN_B, 256, 0, stream>>>(deg, bsum, row_ptr, cursor);
    gat_scatter_r15<<<(EE + 255) / 256, 256, 0, stream>>>(src, dst, cursor, esrc);

    // Layer 1: P = x @ W1 + b1   [50000,128]@[128,256], A fp32, BN=128
    gat_gemm128_r15<0><<<dim3((NN + 63) / 64, 2), 256, 0, stream>>>(x, W1t, b1, P, NN, 128, 256);
    gat_attn8_r15<<<NN / 4, 256, 0, stream>>>((const uint4*)P, row_ptr, esrc, attn1, (uint4*)Q);

    // Layer 2: P = Q @ W2 + b2   [50000,256]@[256,256], A f16, BN=128
    gat_gemm128_r15<1><<<dim3((NN + 63) / 64, 2), 256, 0, stream>>>(Q, W2t, b2, P, NN, 256, 256);
    gat_attn8_r15<<<NN / 4, 256, 0, stream>>>((const uint4*)P, row_ptr, esrc, attn2, (uint4*)Q);

    // Layer 3: h3 = Q @ W3 + b3  [50000,256]@[256,64], A f16, BN=64; attention + graph max-pool
    gat_gemm64_r15<<<dim3((NN + 63) / 64, 1), 256, 0, stream>>>(Q, W3t, b3, h3, NN, 256, 64);
    gat_attn1_r15<<<A1_BLOCKS, 256, 0, stream>>>((const uint2*)h3, row_ptr, esrc, attn3, blockmax);

    gat_final_r15<<<1, 1024, 0, stream>>>(blockmax, out);
}

// Round 16
// 427.762 us; speedup vs baseline: 1.0312x; 1.0312x over previous
//
#include <hip/hip_runtime.h>
#include <hip/hip_bf16.h>

typedef unsigned int u32;
typedef unsigned short u16;
typedef _Float16 f16x2 __attribute__((ext_vector_type(2)));
typedef _Float16 f16x8 __attribute__((ext_vector_type(8)));
typedef float f32x4 __attribute__((ext_vector_type(4)));

#define NN 50000
#define EE 800000
#define A1_BLOCKS 4096
#define SCAN_B ((NN + 255) / 256)     // 196
#define G1_TILES (((NN + 63) / 64) * 2)   // 1564 gemm1 blocks (BN=128, Nc=256)
#define CNT_B ((EE + 255) / 256)      // 3125 count blocks

__device__ __forceinline__ f16x2 ash(u32 u) { union { u32 u; f16x2 h; } c; c.u = u; return c.h; }
__device__ __forceinline__ u32 h2u(f16x2 h) { union { u32 u; f16x2 h; } c; c.h = h; return c.u; }
__device__ __forceinline__ u16 f2h(float v) { _Float16 h = (_Float16)v; return *(u16*)&h; }
__device__ __forceinline__ u32 pack2h(float a, float b) {
    return (u32)f2h(a) | ((u32)f2h(b) << 16);
}
__device__ __forceinline__ float elu(float v) { return v > 0.f ? v : __expf(v) - 1.f; }

// ---------------- prep: weight transpose->f16 (blocks 0-575) + deg zero (blocks 576+) ----------------

__global__ __launch_bounds__(256) void gat_prep_r16(const float* __restrict__ W1,
                                                    const float* __restrict__ W2,
                                                    const float* __restrict__ W3,
                                                    u16* __restrict__ W1t,
                                                    u16* __restrict__ W2t,
                                                    u16* __restrict__ W3t,
                                                    int* __restrict__ deg) {
    int b = blockIdx.x, t = threadIdx.x;
    if (b < 256) {
        if (t < 128) W1t[(long)b * 128 + t] = f2h(W1[(long)t * 256 + b]);
    } else if (b < 512) {
        int n = b - 256;
        W2t[(long)n * 256 + t] = f2h(W2[(long)t * 256 + n]);
    } else if (b < 576) {
        int n = b - 512;
        W3t[(long)n * 256 + t] = f2h(W3[(long)t * 64 + n]);
    } else {
        int i = (b - 576) * 256 + t;
        if (i < NN) deg[i] = 0;
    }
}

// ---------------- MFMA GEMM BN=128 body (shared by fused layer-1 and layer-2) ----------------
// BM=64, BN=128, BK=32, 4 waves; wave w covers cols [32w,32w+32) x all 64 rows.

template <int AHF>
__device__ __forceinline__ void gemm128_body(const void* __restrict__ Ain,
                                             const u16* __restrict__ Wt,
                                             const float* __restrict__ bias,
                                             u16* __restrict__ C,
                                             int M, int K, int Nc,
                                             int bm, int bn) {
    __shared__ __align__(16) u16 As[64 * 40];
    __shared__ __align__(16) u16 Bs[128 * 40];
    const int t    = threadIdx.x;
    const int w    = t >> 6;
    const int lane = t & 63;
    const int sm   = t >> 2;
    const int sk   = (t & 3) * 8;
    const int fq   = (lane >> 4) * 8;
    const int fr   = lane & 15;
    const int nbase = w * 32;

    f32x4 acc[4][2] = {};

    for (int k0 = 0; k0 < K; k0 += 32) {
        {
            int gr = bm + sm;
            f16x8 av = {};
            if (gr < M) {
                if (AHF) {
                    av = *(const f16x8*)((const u16*)Ain + (long)gr * K + k0 + sk);
                } else {
                    const float* p = (const float*)Ain + (long)gr * K + k0 + sk;
                    #pragma unroll
                    for (int i = 0; i < 8; ++i) av[i] = (_Float16)p[i];
                }
            }
            *(f16x8*)&As[sm * 40 + sk] = av;
        }
        #pragma unroll
        for (int i = 0; i < 2; ++i) {
            int tau = t + i * 256;
            int row = tau >> 2, ck = (tau & 3) * 8;
            f16x8 bv = *(const f16x8*)(Wt + (long)(bn + row) * K + k0 + ck);
            *(f16x8*)&Bs[row * 40 + ck] = bv;
        }
        __syncthreads();
        f16x8 afr[4], bfr[2];
        #pragma unroll
        for (int mt = 0; mt < 4; ++mt)
            afr[mt] = *(const f16x8*)&As[(mt * 16 + fr) * 40 + fq];
        #pragma unroll
        for (int nt = 0; nt < 2; ++nt)
            bfr[nt] = *(const f16x8*)&Bs[(nbase + nt * 16 + fr) * 40 + fq];
        #pragma unroll
        for (int mt = 0; mt < 4; ++mt)
            #pragma unroll
            for (int nt = 0; nt < 2; ++nt)
                acc[mt][nt] = __builtin_amdgcn_mfma_f32_16x16x32_f16(
                    afr[mt], bfr[nt], acc[mt][nt], 0, 0, 0);
        __syncthreads();
    }
    #pragma unroll
    for (int mt = 0; mt < 4; ++mt) {
        #pragma unroll
        for (int r = 0; r < 4; ++r) {
            int row = bm + mt * 16 + (lane >> 4) * 4 + r;
            if (row >= M) continue;
            #pragma unroll
            for (int nt = 0; nt < 2; ++nt) {
                int col = bn + nbase + nt * 16 + fr;
                C[(long)row * Nc + col] = f2h(acc[mt][nt][r] + bias[col]);
            }
        }
    }
}

// ---------------- fused: layer-1 GEMM (blocks 0..G1_TILES-1) + degree count (rest) ----------------
// Both depend only on prep; fusing runs the CSR count concurrently under the GEMM.

__global__ __launch_bounds__(256) void gat_fuse1_r16(const float* __restrict__ x,
                                                     const u16* __restrict__ W1t,
                                                     const float* __restrict__ b1,
                                                     u16* __restrict__ P,
                                                     const int* __restrict__ dst,
                                                     int* __restrict__ deg) {
    int b = blockIdx.x;
    if (b < G1_TILES) {
        int bm = (b >> 1) * 64;
        int bn = (b & 1) * 128;
        gemm128_body<0>(x, W1t, b1, P, NN, 128, 256, bm, bn);
    } else {
        int e = (b - G1_TILES) * 256 + threadIdx.x;
        if (e < EE) atomicAdd(&deg[dst[e]], 1);
    }
}

// ---------------- layer-2 GEMM dispatch (BN=128) ----------------

__global__ __launch_bounds__(256) void gat_gemm2_r16(const u16* __restrict__ Q,
                                                     const u16* __restrict__ W2t,
                                                     const float* __restrict__ b2,
                                                     u16* __restrict__ P) {
    gemm128_body<1>(Q, W2t, b2, P, NN, 256, 256, blockIdx.x * 64, blockIdx.y * 128);
}

// ---------------- CSR scan + scatter ----------------

__global__ __launch_bounds__(256) void gat_scana_r16(const int* __restrict__ deg,
                                                     int* __restrict__ bsum) {
    __shared__ int s[256];
    int t = threadIdx.x;
    int i = blockIdx.x * 256 + t;
    s[t] = (i < NN) ? deg[i] : 0;
    __syncthreads();
    for (int o = 128; o > 0; o >>= 1) {
        if (t < o) s[t] += s[t + o];
        __syncthreads();
    }
    if (t == 0) bsum[blockIdx.x] = s[0];
}

__global__ __launch_bounds__(256) void gat_scanc_r16(const int* __restrict__ deg,
                                                     const int* __restrict__ bsum,
                                                     int* __restrict__ row_ptr,
                                                     int* __restrict__ cursor) {
    __shared__ int sb[256];
    __shared__ int s[256];
    int t = threadIdx.x;
    sb[t] = (t < SCAN_B) ? bsum[t] : 0;
    __syncthreads();
    for (int o = 1; o < 256; o <<= 1) {
        int u = (t >= o) ? sb[t - o] : 0;
        __syncthreads();
        sb[t] += u;
        __syncthreads();
    }
    int boff = (blockIdx.x == 0) ? 0 : sb[blockIdx.x - 1];
    if (blockIdx.x == 0 && t == 0) row_ptr[NN] = sb[SCAN_B - 1];
    int i = blockIdx.x * 256 + t;
    int v = (i < NN) ? deg[i] : 0;
    s[t] = v;
    __syncthreads();
    for (int o = 1; o < 256; o <<= 1) {
        int u = (t >= o) ? s[t - o] : 0;
        __syncthreads();
        s[t] += u;
        __syncthreads();
    }
    if (i < NN) {
        int excl = s[t] - v + boff;
        row_ptr[i] = excl;
        cursor[i]  = excl;
    }
}

__global__ void gat_scatter_r16(const int* __restrict__ src, const int* __restrict__ dst,
                                int* __restrict__ cursor, int* __restrict__ esrc) {
    int e = blockIdx.x * 256 + threadIdx.x;
    if (e < EE) {
        int pos = atomicAdd(&cursor[dst[e]], 1);
        esrc[pos] = src[e];
    }
}

// ---------------- MFMA GEMM, BN=64 (verified) — layer 3 (Nc=64) ----------------

__global__ __launch_bounds__(256) void gat_gemm64_r16(const u16* __restrict__ Ain,
                                                      const u16* __restrict__ Wt,
                                                      const float* __restrict__ bias,
                                                      u16* __restrict__ C,
                                                      int M, int K, int Nc) {
    __shared__ __align__(16) u16 As[64 * 40];
    __shared__ __align__(16) u16 Bs[64 * 40];
    const int t    = threadIdx.x;
    const int bm   = blockIdx.x * 64;
    const int bn   = blockIdx.y * 64;
    const int w    = t >> 6;
    const int lane = t & 63;
    const int sm   = t >> 2;
    const int sk   = (t & 3) * 8;
    const int mbase = (w & 1) * 32;
    const int nbase = (w >> 1) * 32;
    const int fq    = (lane >> 4) * 8;
    const int fr    = lane & 15;

    f32x4 acc[2][2] = {};

    for (int k0 = 0; k0 < K; k0 += 32) {
        {
            int gr = bm + sm;
            f16x8 av = {};
            if (gr < M) av = *(const f16x8*)(Ain + (long)gr * K + k0 + sk);
            *(f16x8*)&As[sm * 40 + sk] = av;
        }
        {
            f16x8 bv = *(const f16x8*)(Wt + (long)(bn + sm) * K + k0 + sk);
            *(f16x8*)&Bs[sm * 40 + sk] = bv;
        }
        __syncthreads();
        f16x8 afr[2], bfr[2];
        #pragma unroll
        for (int mt = 0; mt < 2; ++mt)
            afr[mt] = *(const f16x8*)&As[(mbase + mt * 16 + fr) * 40 + fq];
        #pragma unroll
        for (int nt = 0; nt < 2; ++nt)
            bfr[nt] = *(const f16x8*)&Bs[(nbase + nt * 16 + fr) * 40 + fq];
        #pragma unroll
        for (int mt = 0; mt < 2; ++mt)
            #pragma unroll
            for (int nt = 0; nt < 2; ++nt)
                acc[mt][nt] = __builtin_amdgcn_mfma_f32_16x16x32_f16(
                    afr[mt], bfr[nt], acc[mt][nt], 0, 0, 0);
        __syncthreads();
    }
    #pragma unroll
    for (int mt = 0; mt < 2; ++mt) {
        #pragma unroll
        for (int r = 0; r < 4; ++r) {
            int row = bm + mbase + mt * 16 + (lane >> 4) * 4 + r;
            if (row >= M) continue;
            #pragma unroll
            for (int nt = 0; nt < 2; ++nt) {
                int col = bn + nbase + nt * 16 + fr;
                C[(long)row * Nc + col] = f2h(acc[mt][nt][r] + bias[col]);
            }
        }
    }
}

// ---------------- Attention layers 1&2 (R14-verified body): half-wave pairing, packed f16 ----------

__global__ __launch_bounds__(256) void gat_attn8_r16(const uint4* __restrict__ h4,
                                                     const int* __restrict__ row_ptr,
                                                     const int* __restrict__ esrc,
                                                     const float* __restrict__ attn,
                                                     uint4* __restrict__ act4) {
    int t = threadIdx.x;
    int lane = t & 63, wv = t >> 6;
    int hf = lane >> 5, sub = lane & 31;
    int n = blockIdx.x * 4 + wv;          // grid = NN/4 exactly
    float4 av0 = ((const float4*)attn)[sub * 2];
    float4 av1 = ((const float4*)attn)[sub * 2 + 1];
    f16x2 aw0 = {(_Float16)av0.x, (_Float16)av0.y};
    f16x2 aw1 = {(_Float16)av0.z, (_Float16)av0.w};
    f16x2 aw2 = {(_Float16)av1.x, (_Float16)av1.y};
    f16x2 aw3 = {(_Float16)av1.z, (_Float16)av1.w};
    const f16x2 c02 = {(_Float16)0.2f, (_Float16)0.2f};
    uint4 ud = h4[(long)n * 32 + sub];
    f16x2 hd0 = ash(ud.x), hd1 = ash(ud.y), hd2 = ash(ud.z), hd3 = ash(ud.w);
    int lo = row_ptr[n], hi = row_ptr[n + 1];
    float l = 0.f;
    f16x2 O0 = {}, O1 = {}, O2 = {}, O3 = {};
    int e = lo;
    for (; e + 1 < hi; e += 2) {
        int s0 = __builtin_amdgcn_readfirstlane(esrc[e]);
        int s1 = __builtin_amdgcn_readfirstlane(esrc[e + 1]);
        int srow = hf ? s1 : s0;
        uint4 u = h4[(long)srow * 32 + sub];
        f16x2 x0 = ash(u.x), x1 = ash(u.y), x2 = ash(u.z), x3 = ash(u.w);
        f16x2 v0 = x0 + hd0, v1 = x1 + hd1, v2 = x2 + hd2, v3 = x3 + hd3;
        f16x2 r0 = __builtin_elementwise_max(v0, v0 * c02);
        f16x2 r1 = __builtin_elementwise_max(v1, v1 * c02);
        f16x2 r2 = __builtin_elementwise_max(v2, v2 * c02);
        f16x2 r3 = __builtin_elementwise_max(v3, v3 * c02);
        f16x2 acc = r0 * aw0;
        acc += r1 * aw1;
        acc += r2 * aw2;
        acc += r3 * aw3;
        float p = (float)acc.x + (float)acc.y;
        p += __shfl_xor(p, 1);
        p += __shfl_xor(p, 2);
        float w = __expf(p);
        l += w;
        _Float16 wh = (_Float16)w;
        f16x2 w2 = {wh, wh};
        O0 += x0 * w2; O1 += x1 * w2; O2 += x2 * w2; O3 += x3 * w2;
    }
    if (e < hi) {  // odd tail: upper half contributes 0
        int s0 = __builtin_amdgcn_readfirstlane(esrc[e]);
        uint4 u = h4[(long)s0 * 32 + sub];
        f16x2 x0 = ash(u.x), x1 = ash(u.y), x2 = ash(u.z), x3 = ash(u.w);
        f16x2 v0 = x0 + hd0, v1 = x1 + hd1, v2 = x2 + hd2, v3 = x3 + hd3;
        f16x2 r0 = __builtin_elementwise_max(v0, v0 * c02);
        f16x2 r1 = __builtin_elementwise_max(v1, v1 * c02);
        f16x2 r2 = __builtin_elementwise_max(v2, v2 * c02);
        f16x2 r3 = __builtin_elementwise_max(v3, v3 * c02);
        f16x2 acc = r0 * aw0;
        acc += r1 * aw1;
        acc += r2 * aw2;
        acc += r3 * aw3;
        float p = (float)acc.x + (float)acc.y;
        p += __shfl_xor(p, 1);
        p += __shfl_xor(p, 2);
        float w = hf ? 0.f : __expf(p);
        l += w;
        _Float16 wh = (_Float16)w;
        f16x2 w2 = {wh, wh};
        O0 += x0 * w2; O1 += x1 * w2; O2 += x2 * w2; O3 += x3 * w2;
    }
    // merge halves
    l += __shfl_xor(l, 32);
    O0 += ash(__shfl_xor((int)h2u(O0), 32));
    O1 += ash(__shfl_xor((int)h2u(O1), 32));
    O2 += ash(__shfl_xor((int)h2u(O2), 32));
    O3 += ash(__shfl_xor((int)h2u(O3), 32));
    float rinv = 1.f / l;
    if (hf == 0) {
        uint4 outv;
        outv.x = pack2h(elu((float)O0.x * rinv), elu((float)O0.y * rinv));
        outv.y = pack2h(elu((float)O1.x * rinv), elu((float)O1.y * rinv));
        outv.z = pack2h(elu((float)O2.x * rinv), elu((float)O2.y * rinv));
        outv.w = pack2h(elu((float)O3.x * rinv), elu((float)O3.y * rinv));
        act4[(long)n * 32 + sub] = outv;
    }
}

// ---------------- Attention layer 3 (R14-verified body): quarter-wave + max-pool ----------------

__global__ __launch_bounds__(256) void gat_attn1_r16(const uint2* __restrict__ h2,
                                                     const int* __restrict__ row_ptr,
                                                     const int* __restrict__ esrc,
                                                     const float* __restrict__ attn,
                                                     float* __restrict__ blockmax) {
    int t = threadIdx.x;
    int lane = t & 63, wv = t >> 6;
    int g = lane >> 4, sub = lane & 15;
    float4 aq = ((const float4*)attn)[sub];
    f16x2 aw0 = {(_Float16)aq.x, (_Float16)aq.y};
    f16x2 aw1 = {(_Float16)aq.z, (_Float16)aq.w};
    const f16x2 c02 = {(_Float16)0.2f, (_Float16)0.2f};
    float b0 = -1e30f, b1 = -1e30f, b2 = -1e30f, b3 = -1e30f;
    for (int n = blockIdx.x * 4 + wv; n < NN; n += gridDim.x * 4) {
        uint2 ud = h2[(long)n * 16 + sub];
        f16x2 hd0 = ash(ud.x), hd1 = ash(ud.y);
        int lo = row_ptr[n], hi = row_ptr[n + 1];
        float l = 0.f;
        f16x2 O0 = {}, O1 = {};
        for (int e = lo; e < hi; e += 4) {
            int eg = e + g;
            bool valid = eg < hi;
            int s = esrc[valid ? eg : hi - 1];
            uint2 u = h2[(long)s * 16 + sub];
            f16x2 x0 = ash(u.x), x1 = ash(u.y);
            f16x2 v0 = x0 + hd0, v1 = x1 + hd1;
            f16x2 r0 = __builtin_elementwise_max(v0, v0 * c02);
            f16x2 r1 = __builtin_elementwise_max(v1, v1 * c02);
            f16x2 acc = r0 * aw0;
            acc += r1 * aw1;
            float p = (float)acc.x + (float)acc.y;
            p += __shfl_xor(p, 1);
            p += __shfl_xor(p, 2);
            p += __shfl_xor(p, 4);
            p += __shfl_xor(p, 8);
            float w = valid ? __expf(p) : 0.f;
            l += w;
            _Float16 wh = (_Float16)w;
            f16x2 w2 = {wh, wh};
            O0 += x0 * w2;
            O1 += x1 * w2;
        }
        l += __shfl_xor(l, 16); l += __shfl_xor(l, 32);
        O0 += ash(__shfl_xor((int)h2u(O0), 16));
        O0 += ash(__shfl_xor((int)h2u(O0), 32));
        O1 += ash(__shfl_xor((int)h2u(O1), 16));
        O1 += ash(__shfl_xor((int)h2u(O1), 32));
        float rinv = 1.f / l;
        b0 = fmaxf(b0, (float)O0.x * rinv); b1 = fmaxf(b1, (float)O0.y * rinv);
        b2 = fmaxf(b2, (float)O1.x * rinv); b3 = fmaxf(b3, (float)O1.y * rinv);
    }
    __shared__ float4 sm4[4][16];
    if (lane < 16) { float4 v; v.x = b0; v.y = b1; v.z = b2; v.w = b3; sm4[wv][sub] = v; }
    __syncthreads();
    if (wv == 0 && lane < 16) {
        float4 r = sm4[0][sub];
        #pragma unroll
        for (int i = 1; i < 4; ++i) {
            float4 q = sm4[i][sub];
            r.x = fmaxf(r.x, q.x); r.y = fmaxf(r.y, q.y);
            r.z = fmaxf(r.z, q.z); r.w = fmaxf(r.w, q.w);
        }
        ((float4*)(blockmax + (long)blockIdx.x * 64))[sub] = r;
    }
}

__global__ __launch_bounds__(1024) void gat_final_r16(const float* __restrict__ blockmax,
                                                      float* __restrict__ out) {
    __shared__ float sm[16][64];
    int t = threadIdx.x;
    int lane = t & 63, wv = t >> 6;
    float v = -1e30f;
    for (int b = wv; b < A1_BLOCKS; b += 16)
        v = fmaxf(v, blockmax[(long)b * 64 + lane]);
    sm[wv][lane] = v;
    __syncthreads();
    if (wv == 0) {
        float r = sm[0][lane];
        #pragma unroll
        for (int i = 1; i < 16; ++i) r = fmaxf(r, sm[i][lane]);
        out[lane] = r;
    }
}

// ---------------- launch ----------------

extern "C" void kernel_launch(void* const* d_in, const int* in_sizes, int n_in,
                              void* d_out, int out_size, void* d_ws, size_t ws_size,
                              hipStream_t stream) {
    const float* x     = (const float*)d_in[0];
    const int*   src   = (const int*)  d_in[1];
    const int*   dst   = (const int*)  d_in[2];
    const float* W1    = (const float*)d_in[3];
    const float* b1    = (const float*)d_in[4];
    const float* attn1 = (const float*)d_in[5];
    const float* W2    = (const float*)d_in[6];
    const float* b2    = (const float*)d_in[7];
    const float* attn2 = (const float*)d_in[8];
    const float* W3    = (const float*)d_in[9];
    const float* b3    = (const float*)d_in[10];
    const float* attn3 = (const float*)d_in[11];
    float* out = (float*)d_out;

    char* ws = (char*)d_ws;
    size_t off = 0;
    auto carve = [&](size_t bytes) { void* p = ws + off; off += (bytes + 255) & ~size_t(255); return p; };
    u16*   P        = (u16*)  carve((size_t)NN * 256 * 2);
    u16*   Q        = (u16*)  carve((size_t)NN * 256 * 2);
    u16*   h3       = (u16*)  carve((size_t)NN * 64 * 2);
    int*   row_ptr  = (int*)  carve((size_t)(NN + 1) * 4);
    int*   deg      = (int*)  carve((size_t)NN * 4);
    int*   cursor   = (int*)  carve((size_t)NN * 4);
    int*   esrc     = (int*)  carve((size_t)EE * 4);
    float* blockmax = (float*)carve((size_t)A1_BLOCKS * 64 * 4);
    int*   bsum     = (int*)  carve((size_t)SCAN_B * 4);
    u16*   W1t      = (u16*)  carve((size_t)256 * 128 * 2);
    u16*   W2t      = (u16*)  carve((size_t)256 * 256 * 2);
    u16*   W3t      = (u16*)  carve((size_t)64 * 256 * 2);

    // prep (weights + deg zero)
    gat_prep_r16<<<576 + SCAN_B, 256, 0, stream>>>(W1, W2, W3, W1t, W2t, W3t, deg);
    // fused: layer-1 GEMM + degree count (independent, hidden under the GEMM)
    gat_fuse1_r16<<<G1_TILES + CNT_B, 256, 0, stream>>>(x, W1t, b1, P, dst, deg);
    gat_scana_r16<<<SCAN_B, 256, 0, stream>>>(deg, bsum);
    gat_scanc_r16<<<SCAN_B, 256, 0, stream>>>(deg, bsum, row_ptr, cursor);
    gat_scatter_r16<<<CNT_B, 256, 0, stream>>>(src, dst, cursor, esrc);

    // Layer 1 attention
    gat_attn8_r16<<<NN / 4, 256, 0, stream>>>((const uint4*)P, row_ptr, esrc, attn1, (uint4*)Q);

    // Layer 2
    gat_gemm2_r16<<<dim3((NN + 63) / 64, 2), 256, 0, stream>>>(Q, W2t, b2, P);
    gat_attn8_r16<<<NN / 4, 256, 0, stream>>>((const uint4*)P, row_ptr, esrc, attn2, (uint4*)Q);

    // Layer 3
    gat_gemm64_r16<<<dim3((NN + 63) / 64, 1), 256, 0, stream>>>(Q, W3t, b3, h3, NN, 256, 64);
    gat_attn1_r16<<<A1_BLOCKS, 256, 0, stream>>>((const uint2*)h3, row_ptr, esrc, attn3, blockmax);

    gat_final_r16<<<1, 1024, 0, stream>>>(blockmax, out);
}

// Round 17
// 416.890 us; speedup vs baseline: 1.0581x; 1.0261x over previous
//
#include <hip/hip_runtime.h>
#include <hip/hip_bf16.h>

typedef unsigned int u32;
typedef unsigned short u16;
typedef _Float16 f16x2 __attribute__((ext_vector_type(2)));
typedef _Float16 f16x8 __attribute__((ext_vector_type(8)));
typedef float f32x4 __attribute__((ext_vector_type(4)));

#define NN 50000
#define EE 800000
#define A1_BLOCKS 4096
#define SCAN_B ((NN + 255) / 256)     // 196
#define G1_TILES (((NN + 63) / 64) * 2)   // 1564 gemm1 blocks (BN=128, Nc=256)
#define CNT_B ((EE + 255) / 256)      // 3125 count blocks

__device__ __forceinline__ f16x2 ash(u32 u) { union { u32 u; f16x2 h; } c; c.u = u; return c.h; }
__device__ __forceinline__ u32 h2u(f16x2 h) { union { u32 u; f16x2 h; } c; c.h = h; return c.u; }
__device__ __forceinline__ u16 f2h(float v) { _Float16 h = (_Float16)v; return *(u16*)&h; }
__device__ __forceinline__ u32 pack2h(float a, float b) {
    return (u32)f2h(a) | ((u32)f2h(b) << 16);
}
__device__ __forceinline__ float elu(float v) { return v > 0.f ? v : __expf(v) - 1.f; }

// ---------------- prep: weight transpose->f16 (blocks 0-575) + deg zero (blocks 576+) ----------------

__global__ __launch_bounds__(256) void gat_prep_r17(const float* __restrict__ W1,
                                                    const float* __restrict__ W2,
                                                    const float* __restrict__ W3,
                                                    u16* __restrict__ W1t,
                                                    u16* __restrict__ W2t,
                                                    u16* __restrict__ W3t,
                                                    int* __restrict__ deg) {
    int b = blockIdx.x, t = threadIdx.x;
    if (b < 256) {
        if (t < 128) W1t[(long)b * 128 + t] = f2h(W1[(long)t * 256 + b]);
    } else if (b < 512) {
        int n = b - 256;
        W2t[(long)n * 256 + t] = f2h(W2[(long)t * 256 + n]);
    } else if (b < 576) {
        int n = b - 512;
        W3t[(long)n * 256 + t] = f2h(W3[(long)t * 64 + n]);
    } else {
        int i = (b - 576) * 256 + t;
        if (i < NN) deg[i] = 0;
    }
}

// ---------------- MFMA GEMM BN=128 body (shared by fused layer-1 and layer-2) ----------------

template <int AHF>
__device__ __forceinline__ void gemm128_body(const void* __restrict__ Ain,
                                             const u16* __restrict__ Wt,
                                             const float* __restrict__ bias,
                                             u16* __restrict__ C,
                                             int M, int K, int Nc,
                                             int bm, int bn) {
    __shared__ __align__(16) u16 As[64 * 40];
    __shared__ __align__(16) u16 Bs[128 * 40];
    const int t    = threadIdx.x;
    const int w    = t >> 6;
    const int lane = t & 63;
    const int sm   = t >> 2;
    const int sk   = (t & 3) * 8;
    const int fq   = (lane >> 4) * 8;
    const int fr   = lane & 15;
    const int nbase = w * 32;

    f32x4 acc[4][2] = {};

    for (int k0 = 0; k0 < K; k0 += 32) {
        {
            int gr = bm + sm;
            f16x8 av = {};
            if (gr < M) {
                if (AHF) {
                    av = *(const f16x8*)((const u16*)Ain + (long)gr * K + k0 + sk);
                } else {
                    const float* p = (const float*)Ain + (long)gr * K + k0 + sk;
                    #pragma unroll
                    for (int i = 0; i < 8; ++i) av[i] = (_Float16)p[i];
                }
            }
            *(f16x8*)&As[sm * 40 + sk] = av;
        }
        #pragma unroll
        for (int i = 0; i < 2; ++i) {
            int tau = t + i * 256;
            int row = tau >> 2, ck = (tau & 3) * 8;
            f16x8 bv = *(const f16x8*)(Wt + (long)(bn + row) * K + k0 + ck);
            *(f16x8*)&Bs[row * 40 + ck] = bv;
        }
        __syncthreads();
        f16x8 afr[4], bfr[2];
        #pragma unroll
        for (int mt = 0; mt < 4; ++mt)
            afr[mt] = *(const f16x8*)&As[(mt * 16 + fr) * 40 + fq];
        #pragma unroll
        for (int nt = 0; nt < 2; ++nt)
            bfr[nt] = *(const f16x8*)&Bs[(nbase + nt * 16 + fr) * 40 + fq];
        #pragma unroll
        for (int mt = 0; mt < 4; ++mt)
            #pragma unroll
            for (int nt = 0; nt < 2; ++nt)
                acc[mt][nt] = __builtin_amdgcn_mfma_f32_16x16x32_f16(
                    afr[mt], bfr[nt], acc[mt][nt], 0, 0, 0);
        __syncthreads();
    }
    #pragma unroll
    for (int mt = 0; mt < 4; ++mt) {
        #pragma unroll
        for (int r = 0; r < 4; ++r) {
            int row = bm + mt * 16 + (lane >> 4) * 4 + r;
            if (row >= M) continue;
            #pragma unroll
            for (int nt = 0; nt < 2; ++nt) {
                int col = bn + nbase + nt * 16 + fr;
                C[(long)row * Nc + col] = f2h(acc[mt][nt][r] + bias[col]);
            }
        }
    }
}

// ---------------- fused: layer-1 GEMM + degree count (independent, concurrent) ----------------

__global__ __launch_bounds__(256) void gat_fuse1_r17(const float* __restrict__ x,
                                                     const u16* __restrict__ W1t,
                                                     const float* __restrict__ b1,
                                                     u16* __restrict__ P,
                                                     const int* __restrict__ dst,
                                                     int* __restrict__ deg) {
    int b = blockIdx.x;
    if (b < G1_TILES) {
        int bm = (b >> 1) * 64;
        int bn = (b & 1) * 128;
        gemm128_body<0>(x, W1t, b1, P, NN, 128, 256, bm, bn);
    } else {
        int e = (b - G1_TILES) * 256 + threadIdx.x;
        if (e < EE) atomicAdd(&deg[dst[e]], 1);
    }
}

__global__ __launch_bounds__(256) void gat_gemm2_r17(const u16* __restrict__ Q,
                                                     const u16* __restrict__ W2t,
                                                     const float* __restrict__ b2,
                                                     u16* __restrict__ P) {
    gemm128_body<1>(Q, W2t, b2, P, NN, 256, 256, blockIdx.x * 64, blockIdx.y * 128);
}

// ---------------- CSR scan + scatter ----------------

__global__ __launch_bounds__(256) void gat_scana_r17(const int* __restrict__ deg,
                                                     int* __restrict__ bsum) {
    __shared__ int s[256];
    int t = threadIdx.x;
    int i = blockIdx.x * 256 + t;
    s[t] = (i < NN) ? deg[i] : 0;
    __syncthreads();
    for (int o = 128; o > 0; o >>= 1) {
        if (t < o) s[t] += s[t + o];
        __syncthreads();
    }
    if (t == 0) bsum[blockIdx.x] = s[0];
}

__global__ __launch_bounds__(256) void gat_scanc_r17(const int* __restrict__ deg,
                                                     const int* __restrict__ bsum,
                                                     int* __restrict__ row_ptr,
                                                     int* __restrict__ cursor) {
    __shared__ int sb[256];
    __shared__ int s[256];
    int t = threadIdx.x;
    sb[t] = (t < SCAN_B) ? bsum[t] : 0;
    __syncthreads();
    for (int o = 1; o < 256; o <<= 1) {
        int u = (t >= o) ? sb[t - o] : 0;
        __syncthreads();
        sb[t] += u;
        __syncthreads();
    }
    int boff = (blockIdx.x == 0) ? 0 : sb[blockIdx.x - 1];
    if (blockIdx.x == 0 && t == 0) row_ptr[NN] = sb[SCAN_B - 1];
    int i = blockIdx.x * 256 + t;
    int v = (i < NN) ? deg[i] : 0;
    s[t] = v;
    __syncthreads();
    for (int o = 1; o < 256; o <<= 1) {
        int u = (t >= o) ? s[t - o] : 0;
        __syncthreads();
        s[t] += u;
        __syncthreads();
    }
    if (i < NN) {
        int excl = s[t] - v + boff;
        row_ptr[i] = excl;
        cursor[i]  = excl;
    }
}

__global__ void gat_scatter_r17(const int* __restrict__ src, const int* __restrict__ dst,
                                int* __restrict__ cursor, int* __restrict__ esrc) {
    int e = blockIdx.x * 256 + threadIdx.x;
    if (e < EE) {
        int pos = atomicAdd(&cursor[dst[e]], 1);
        esrc[pos] = src[e];
    }
}

// ---------------- MFMA GEMM, BN=64 — layer 3 (Nc=64) ----------------

__global__ __launch_bounds__(256) void gat_gemm64_r17(const u16* __restrict__ Ain,
                                                      const u16* __restrict__ Wt,
                                                      const float* __restrict__ bias,
                                                      u16* __restrict__ C,
                                                      int M, int K, int Nc) {
    __shared__ __align__(16) u16 As[64 * 40];
    __shared__ __align__(16) u16 Bs[64 * 40];
    const int t    = threadIdx.x;
    const int bm   = blockIdx.x * 64;
    const int bn   = blockIdx.y * 64;
    const int w    = t >> 6;
    const int lane = t & 63;
    const int sm   = t >> 2;
    const int sk   = (t & 3) * 8;
    const int mbase = (w & 1) * 32;
    const int nbase = (w >> 1) * 32;
    const int fq    = (lane >> 4) * 8;
    const int fr    = lane & 15;

    f32x4 acc[2][2] = {};

    for (int k0 = 0; k0 < K; k0 += 32) {
        {
            int gr = bm + sm;
            f16x8 av = {};
            if (gr < M) av = *(const f16x8*)(Ain + (long)gr * K + k0 + sk);
            *(f16x8*)&As[sm * 40 + sk] = av;
        }
        {
            f16x8 bv = *(const f16x8*)(Wt + (long)(bn + sm) * K + k0 + sk);
            *(f16x8*)&Bs[sm * 40 + sk] = bv;
        }
        __syncthreads();
        f16x8 afr[2], bfr[2];
        #pragma unroll
        for (int mt = 0; mt < 2; ++mt)
            afr[mt] = *(const f16x8*)&As[(mbase + mt * 16 + fr) * 40 + fq];
        #pragma unroll
        for (int nt = 0; nt < 2; ++nt)
            bfr[nt] = *(const f16x8*)&Bs[(nbase + nt * 16 + fr) * 40 + fq];
        #pragma unroll
        for (int mt = 0; mt < 2; ++mt)
            #pragma unroll
            for (int nt = 0; nt < 2; ++nt)
                acc[mt][nt] = __builtin_amdgcn_mfma_f32_16x16x32_f16(
                    afr[mt], bfr[nt], acc[mt][nt], 0, 0, 0);
        __syncthreads();
    }
    #pragma unroll
    for (int mt = 0; mt < 2; ++mt) {
        #pragma unroll
        for (int r = 0; r < 4; ++r) {
            int row = bm + mbase + mt * 16 + (lane >> 4) * 4 + r;
            if (row >= M) continue;
            #pragma unroll
            for (int nt = 0; nt < 2; ++nt) {
                int col = bn + nbase + nt * 16 + fr;
                C[(long)row * Nc + col] = f2h(acc[mt][nt][r] + bias[col]);
            }
        }
    }
}

// ---------------- Attention layers 1&2: half-wave pairing, packed f16, batched index broadcast ------
// Full batches of 8 edges: one coalesced esrc load into a VGPR, per-pair ds_bpermute
// broadcast (no scalar loads, all 4 gathers address-ready -> MLP). Tail (<8) = R16 code.

__global__ __launch_bounds__(256) void gat_attn8_r17(const uint4* __restrict__ h4,
                                                     const int* __restrict__ row_ptr,
                                                     const int* __restrict__ esrc,
                                                     const float* __restrict__ attn,
                                                     uint4* __restrict__ act4) {
    int t = threadIdx.x;
    int lane = t & 63, wv = t >> 6;
    int hf = lane >> 5, sub = lane & 31;
    int n = blockIdx.x * 4 + wv;          // grid = NN/4 exactly
    float4 av0 = ((const float4*)attn)[sub * 2];
    float4 av1 = ((const float4*)attn)[sub * 2 + 1];
    f16x2 aw0 = {(_Float16)av0.x, (_Float16)av0.y};
    f16x2 aw1 = {(_Float16)av0.z, (_Float16)av0.w};
    f16x2 aw2 = {(_Float16)av1.x, (_Float16)av1.y};
    f16x2 aw3 = {(_Float16)av1.z, (_Float16)av1.w};
    const f16x2 c02 = {(_Float16)0.2f, (_Float16)0.2f};
    uint4 ud = h4[(long)n * 32 + sub];
    f16x2 hd0 = ash(ud.x), hd1 = ash(ud.y), hd2 = ash(ud.z), hd3 = ash(ud.w);
    int lo = row_ptr[n], hi = row_ptr[n + 1];
    float l = 0.f;
    f16x2 O0 = {}, O1 = {}, O2 = {}, O3 = {};
    int e = lo;
    // ---- full batches of 8 edges ----
    for (; e + 8 <= hi; e += 8) {
        int myidx = esrc[e + (lane & 7)];   // coalesced; each 8-lane group holds the 8 indices
        #pragma unroll
        for (int j = 0; j < 8; j += 2) {
            int srow = __shfl(myidx, j + hf, 8);   // lower half: edge e+j, upper: e+j+1
            uint4 u = h4[(long)srow * 32 + sub];
            f16x2 x0 = ash(u.x), x1 = ash(u.y), x2 = ash(u.z), x3 = ash(u.w);
            f16x2 v0 = x0 + hd0, v1 = x1 + hd1, v2 = x2 + hd2, v3 = x3 + hd3;
            f16x2 r0 = __builtin_elementwise_max(v0, v0 * c02);
            f16x2 r1 = __builtin_elementwise_max(v1, v1 * c02);
            f16x2 r2 = __builtin_elementwise_max(v2, v2 * c02);
            f16x2 r3 = __builtin_elementwise_max(v3, v3 * c02);
            f16x2 acc = r0 * aw0;
            acc += r1 * aw1;
            acc += r2 * aw2;
            acc += r3 * aw3;
            float p = (float)acc.x + (float)acc.y;
            p += __shfl_xor(p, 1);
            p += __shfl_xor(p, 2);
            float w = __expf(p);
            l += w;
            _Float16 wh = (_Float16)w;
            f16x2 w2 = {wh, wh};
            O0 += x0 * w2; O1 += x1 * w2; O2 += x2 * w2; O3 += x3 * w2;
        }
    }
    // ---- tail pairs (0..7 edges) ----
    for (; e + 1 < hi; e += 2) {
        int s0 = __builtin_amdgcn_readfirstlane(esrc[e]);
        int s1 = __builtin_amdgcn_readfirstlane(esrc[e + 1]);
        int srow = hf ? s1 : s0;
        uint4 u = h4[(long)srow * 32 + sub];
        f16x2 x0 = ash(u.x), x1 = ash(u.y), x2 = ash(u.z), x3 = ash(u.w);
        f16x2 v0 = x0 + hd0, v1 = x1 + hd1, v2 = x2 + hd2, v3 = x3 + hd3;
        f16x2 r0 = __builtin_elementwise_max(v0, v0 * c02);
        f16x2 r1 = __builtin_elementwise_max(v1, v1 * c02);
        f16x2 r2 = __builtin_elementwise_max(v2, v2 * c02);
        f16x2 r3 = __builtin_elementwise_max(v3, v3 * c02);
        f16x2 acc = r0 * aw0;
        acc += r1 * aw1;
        acc += r2 * aw2;
        acc += r3 * aw3;
        float p = (float)acc.x + (float)acc.y;
        p += __shfl_xor(p, 1);
        p += __shfl_xor(p, 2);
        float w = __expf(p);
        l += w;
        _Float16 wh = (_Float16)w;
        f16x2 w2 = {wh, wh};
        O0 += x0 * w2; O1 += x1 * w2; O2 += x2 * w2; O3 += x3 * w2;
    }
    if (e < hi) {  // odd tail: upper half contributes 0
        int s0 = __builtin_amdgcn_readfirstlane(esrc[e]);
        uint4 u = h4[(long)s0 * 32 + sub];
        f16x2 x0 = ash(u.x), x1 = ash(u.y), x2 = ash(u.z), x3 = ash(u.w);
        f16x2 v0 = x0 + hd0, v1 = x1 + hd1, v2 = x2 + hd2, v3 = x3 + hd3;
        f16x2 r0 = __builtin_elementwise_max(v0, v0 * c02);
        f16x2 r1 = __builtin_elementwise_max(v1, v1 * c02);
        f16x2 r2 = __builtin_elementwise_max(v2, v2 * c02);
        f16x2 r3 = __builtin_elementwise_max(v3, v3 * c02);
        f16x2 acc = r0 * aw0;
        acc += r1 * aw1;
        acc += r2 * aw2;
        acc += r3 * aw3;
        float p = (float)acc.x + (float)acc.y;
        p += __shfl_xor(p, 1);
        p += __shfl_xor(p, 2);
        float w = hf ? 0.f : __expf(p);
        l += w;
        _Float16 wh = (_Float16)w;
        f16x2 w2 = {wh, wh};
        O0 += x0 * w2; O1 += x1 * w2; O2 += x2 * w2; O3 += x3 * w2;
    }
    // merge halves
    l += __shfl_xor(l, 32);
    O0 += ash(__shfl_xor((int)h2u(O0), 32));
    O1 += ash(__shfl_xor((int)h2u(O1), 32));
    O2 += ash(__shfl_xor((int)h2u(O2), 32));
    O3 += ash(__shfl_xor((int)h2u(O3), 32));
    float rinv = 1.f / l;
    if (hf == 0) {
        uint4 outv;
        outv.x = pack2h(elu((float)O0.x * rinv), elu((float)O0.y * rinv));
        outv.y = pack2h(elu((float)O1.x * rinv), elu((float)O1.y * rinv));
        outv.z = pack2h(elu((float)O2.x * rinv), elu((float)O2.y * rinv));
        outv.w = pack2h(elu((float)O3.x * rinv), elu((float)O3.y * rinv));
        act4[(long)n * 32 + sub] = outv;
    }
}

// ---------------- Attention layer 3: quarter-wave, packed f16, light index prefetch + max-pool ------

__global__ __launch_bounds__(256) void gat_attn1_r17(const uint2* __restrict__ h2,
                                                     const int* __restrict__ row_ptr,
                                                     const int* __restrict__ esrc,
                                                     const float* __restrict__ attn,
                                                     float* __restrict__ blockmax) {
    int t = threadIdx.x;
    int lane = t & 63, wv = t >> 6;
    int g = lane >> 4, sub = lane & 15;
    float4 aq = ((const float4*)attn)[sub];
    f16x2 aw0 = {(_Float16)aq.x, (_Float16)aq.y};
    f16x2 aw1 = {(_Float16)aq.z, (_Float16)aq.w};
    const f16x2 c02 = {(_Float16)0.2f, (_Float16)0.2f};
    float b0 = -1e30f, b1 = -1e30f, b2 = -1e30f, b3 = -1e30f;
    for (int n = blockIdx.x * 4 + wv; n < NN; n += gridDim.x * 4) {
        uint2 ud = h2[(long)n * 16 + sub];
        f16x2 hd0 = ash(ud.x), hd1 = ash(ud.y);
        int lo = row_ptr[n], hi = row_ptr[n + 1];
        float l = 0.f;
        f16x2 O0 = {}, O1 = {};
        int eg = lo + g;
        int s = esrc[(eg < hi) ? eg : hi - 1];          // index for iter 0
        for (int e = lo; e < hi; e += 4) {
            int egn = e + 4 + g;
            int snext = esrc[(egn < hi) ? egn : hi - 1]; // prefetch next iter's index
            bool valid = e + g < hi;
            uint2 u = h2[(long)s * 16 + sub];
            f16x2 x0 = ash(u.x), x1 = ash(u.y);
            f16x2 v0 = x0 + hd0, v1 = x1 + hd1;
            f16x2 r0 = __builtin_elementwise_max(v0, v0 * c02);
            f16x2 r1 = __builtin_elementwise_max(v1, v1 * c02);
            f16x2 acc = r0 * aw0;
            acc += r1 * aw1;
            float p = (float)acc.x + (float)acc.y;
            p += __shfl_xor(p, 1);
            p += __shfl_xor(p, 2);
            p += __shfl_xor(p, 4);
            p += __shfl_xor(p, 8);
            float w = valid ? __expf(p) : 0.f;
            l += w;
            _Float16 wh = (_Float16)w;
            f16x2 w2 = {wh, wh};
            O0 += x0 * w2;
            O1 += x1 * w2;
            s = snext;
        }
        l += __shfl_xor(l, 16); l += __shfl_xor(l, 32);
        O0 += ash(__shfl_xor((int)h2u(O0), 16));
        O0 += ash(__shfl_xor((int)h2u(O0), 32));
        O1 += ash(__shfl_xor((int)h2u(O1), 16));
        O1 += ash(__shfl_xor((int)h2u(O1), 32));
        float rinv = 1.f / l;
        b0 = fmaxf(b0, (float)O0.x * rinv); b1 = fmaxf(b1, (float)O0.y * rinv);
        b2 = fmaxf(b2, (float)O1.x * rinv); b3 = fmaxf(b3, (float)O1.y * rinv);
    }
    __shared__ float4 sm4[4][16];
    if (lane < 16) { float4 v; v.x = b0; v.y = b1; v.z = b2; v.w = b3; sm4[wv][sub] = v; }
    __syncthreads();
    if (wv == 0 && lane < 16) {
        float4 r = sm4[0][sub];
        #pragma unroll
        for (int i = 1; i < 4; ++i) {
            float4 q = sm4[i][sub];
            r.x = fmaxf(r.x, q.x); r.y = fmaxf(r.y, q.y);
            r.z = fmaxf(r.z, q.z); r.w = fmaxf(r.w, q.w);
        }
        ((float4*)(blockmax + (long)blockIdx.x * 64))[sub] = r;
    }
}

__global__ __launch_bounds__(1024) void gat_final_r17(const float* __restrict__ blockmax,
                                                      float* __restrict__ out) {
    __shared__ float sm[16][64];
    int t = threadIdx.x;
    int lane = t & 63, wv = t >> 6;
    float v = -1e30f;
    for (int b = wv; b < A1_BLOCKS; b += 16)
        v = fmaxf(v, blockmax[(long)b * 64 + lane]);
    sm[wv][lane] = v;
    __syncthreads();
    if (wv == 0) {
        float r = sm[0][lane];
        #pragma unroll
        for (int i = 1; i < 16; ++i) r = fmaxf(r, sm[i][lane]);
        out[lane] = r;
    }
}

// ---------------- launch ----------------

extern "C" void kernel_launch(void* const* d_in, const int* in_sizes, int n_in,
                              void* d_out, int out_size, void* d_ws, size_t ws_size,
                              hipStream_t stream) {
    const float* x     = (const float*)d_in[0];
    const int*   src   = (const int*)  d_in[1];
    const int*   dst   = (const int*)  d_in[2];
    const float* W1    = (const float*)d_in[3];
    const float* b1    = (const float*)d_in[4];
    const float* attn1 = (const float*)d_in[5];
    const float* W2    = (const float*)d_in[6];
    const float* b2    = (const float*)d_in[7];
    const float* attn2 = (const float*)d_in[8];
    const float* W3    = (const float*)d_in[9];
    const float* b3    = (const float*)d_in[10];
    const float* attn3 = (const float*)d_in[11];
    float* out = (float*)d_out;

    char* ws = (char*)d_ws;
    size_t off = 0;
    auto carve = [&](size_t bytes) { void* p = ws + off; off += (bytes + 255) & ~size_t(255); return p; };
    u16*   P        = (u16*)  carve((size_t)NN * 256 * 2);
    u16*   Q        = (u16*)  carve((size_t)NN * 256 * 2);
    u16*   h3       = (u16*)  carve((size_t)NN * 64 * 2);
    int*   row_ptr  = (int*)  carve((size_t)(NN + 1) * 4);
    int*   deg      = (int*)  carve((size_t)NN * 4);
    int*   cursor   = (int*)  carve((size_t)NN * 4);
    int*   esrc     = (int*)  carve((size_t)EE * 4);
    float* blockmax = (float*)carve((size_t)A1_BLOCKS * 64 * 4);
    int*   bsum     = (int*)  carve((size_t)SCAN_B * 4);
    u16*   W1t      = (u16*)  carve((size_t)256 * 128 * 2);
    u16*   W2t      = (u16*)  carve((size_t)256 * 256 * 2);
    u16*   W3t      = (u16*)  carve((size_t)64 * 256 * 2);

    gat_prep_r17<<<576 + SCAN_B, 256, 0, stream>>>(W1, W2, W3, W1t, W2t, W3t, deg);
    gat_fuse1_r17<<<G1_TILES + CNT_B, 256, 0, stream>>>(x, W1t, b1, P, dst, deg);
    gat_scana_r17<<<SCAN_B, 256, 0, stream>>>(deg, bsum);
    gat_scanc_r17<<<SCAN_B, 256, 0, stream>>>(deg, bsum, row_ptr, cursor);
    gat_scatter_r17<<<CNT_B, 256, 0, stream>>>(src, dst, cursor, esrc);

    gat_attn8_r17<<<NN / 4, 256, 0, stream>>>((const uint4*)P, row_ptr, esrc, attn1, (uint4*)Q);

    gat_gemm2_r17<<<dim3((NN + 63) / 64, 2), 256, 0, stream>>>(Q, W2t, b2, P);
    gat_attn8_r17<<<NN / 4, 256, 0, stream>>>((const uint4*)P, row_ptr, esrc, attn2, (uint4*)Q);

    gat_gemm64_r17<<<dim3((NN + 63) / 64, 1), 256, 0, stream>>>(Q, W3t, b3, h3, NN, 256, 64);
    gat_attn1_r17<<<A1_BLOCKS, 256, 0, stream>>>((const uint2*)h3, row_ptr, esrc, attn3, blockmax);

    gat_final_r17<<<1, 1024, 0, stream>>>(blockmax, out);
}